// Round 7
// baseline (138.536 us; speedup 1.0000x reference)
//
#include <hip/hip_runtime.h>

#define L_FFT 4096
#define NCH 512

typedef __attribute__((ext_vector_type(8))) short bf16x8;
typedef __attribute__((ext_vector_type(4))) float f32x4;

__device__ __forceinline__ void split_bf16(float x, unsigned short& h, unsigned short& l) {
  unsigned u = __float_as_uint(x);
  h = (unsigned short)(u >> 16);                    // truncate -> hi
  float fh = __uint_as_float(u & 0xffff0000u);
  float lo = x - fh;                                // exact residual
  l = (unsigned short)(__float_as_uint(lo) >> 16);  // truncate -> lo
}

// ---------------------------------------------------------------------------
// k0a: phase tables ctab/stab[4096] = cos/sin(2*pi*ph/4096)
// ---------------------------------------------------------------------------
__global__ __launch_bounds__(256) void k0a_phase(float* __restrict__ ctab,
                                                 float* __restrict__ stab) {
  int i = blockIdx.x * 256 + threadIdx.x;  // 0..4095
  float s, c;
  sincosf(6.2831853071795864769f / 4096.f * (float)i, &s, &c);
  ctab[i] = c;
  stab[i] = s;
}

// ---------------------------------------------------------------------------
// k0b: expand phase tables into MFMA-fragment-swizzled bf16 hi/lo tables.
// T1f (forward B): idx = ((chunk*2+wn)*4+ni)*512 + lane*8 + i
//   kcol = wn*64+ni*16+(lane&15), l = chunk*32+(lane>>4)*8+i
// T2f (inverse B): idx = (lt16*4+kc2)*512 + lane*8 + i
//   l = lt16*16+(lane&15), k = kc2*32+(lane>>4)*8+i
// ---------------------------------------------------------------------------
__global__ __launch_bounds__(256) void k0b_expand(const int* __restrict__ index,
                                                  const float* __restrict__ ctab,
                                                  const float* __restrict__ stab,
                                                  unsigned short* __restrict__ T1fh,
                                                  unsigned short* __restrict__ T1fl,
                                                  unsigned short* __restrict__ T2fh,
                                                  unsigned short* __restrict__ T2fl) {
  int idx = blockIdx.x * 256 + threadIdx.x;  // 0..524287
  int i = idx & 7, lane = (idx >> 3) & 63;
  int m16 = lane & 15, kg = lane >> 4;
  {
    int ni = (idx >> 9) & 3, wn = (idx >> 11) & 1, chunk = idx >> 12;
    int kcol = wn * 64 + ni * 16 + m16;
    int l = chunk * 32 + kg * 8 + i;
    int f = index[kcol & 63];
    int ph = (l * f) & 4095;
    float v = (kcol < 64) ? ctab[ph] : -stab[ph];
    unsigned short h, lo;
    split_bf16(v, h, lo);
    T1fh[idx] = h;
    T1fl[idx] = lo;
  }
  {
    int kc2 = (idx >> 9) & 3, lt16 = idx >> 11;
    int l = lt16 * 16 + m16;
    int k = kc2 * 32 + kg * 8 + i;
    int ph = (l * (k & 63)) & 4095;
    float v = (k < 64) ? ctab[ph] : stab[ph];
    unsigned short h, lo;
    split_bf16(v, h, lo);
    T2fh[idx] = h;
    T2fl[idx] = lo;
  }
}

// ---------------------------------------------------------------------------
// k1: forward GEMM, zero LDS, 4-buffer static register ring, prefetch dist 2.
// part[p][c][k] = sum_l X[c,l]*T1[k,l]
// Block 64c x 128k (4 waves; wave 32c x 64k as 2x4 of 16x16x32), chunk=32 l.
// ---------------------------------------------------------------------------
__global__ __launch_bounds__(256, 4) void k1_forward(const float* __restrict__ q,
                                                     const unsigned short* __restrict__ T1fh,
                                                     const unsigned short* __restrict__ T1fl,
                                                     float* __restrict__ part,
                                                     int kspan) {
  int ctile = blockIdx.x;  // 0..127
  int p = blockIdx.y;
  int b = ctile >> 3, ch0 = (ctile & 7) * 64;
  int t = threadIdx.x, wave = t >> 6, lane = t & 63;
  int wm = wave >> 1, wn = wave & 1, m16 = lane & 15, kg = lane >> 4;
  int nchunk = kspan >> 5;          // 128/64/32/16 for np=1/2/4/8 (mult of 4)
  int chunk0 = (p * kspan) >> 5;

  const float* qbase = q + (size_t)b * L_FFT * NCH + (size_t)kg * 8 * NCH
                         + (ch0 + wm * 32 + m16);

  float X0[2][8], X1[2][8], X2[2][8], X3[2][8];
  f32x4 acc[2][4] = {};

#define K1_GLOAD(BUF, CHUNK)                                                  \
  do {                                                                        \
    const float* qp_ = qbase + (size_t)(CHUNK) * 32 * NCH;                    \
    _Pragma("unroll") for (int mi_ = 0; mi_ < 2; ++mi_)                       \
      _Pragma("unroll") for (int i_ = 0; i_ < 8; ++i_)                        \
        BUF[mi_][i_] = qp_[i_ * NCH + mi_ * 16];                              \
  } while (0)

#define K1_COMPUTE(BUF, CHUNK)                                                \
  do {                                                                        \
    bf16x8 bh_[4], bl_[4];                                                    \
    _Pragma("unroll") for (int ni_ = 0; ni_ < 4; ++ni_) {                     \
      size_t off_ = ((size_t)(((CHUNK)*2 + wn) * 4 + ni_) << 9) + lane * 8;   \
      bh_[ni_] = *(const bf16x8*)(T1fh + off_);                               \
      bl_[ni_] = *(const bf16x8*)(T1fl + off_);                               \
    }                                                                         \
    _Pragma("unroll") for (int mi_ = 0; mi_ < 2; ++mi_) {                     \
      union { bf16x8 v; unsigned w[4]; } ah_, al_;                            \
      _Pragma("unroll") for (int j_ = 0; j_ < 4; ++j_) {                      \
        float x0_ = BUF[mi_][2 * j_], x1_ = BUF[mi_][2 * j_ + 1];             \
        unsigned u0_ = __float_as_uint(x0_), u1_ = __float_as_uint(x1_);      \
        ah_.w[j_] = (u0_ >> 16) | (u1_ & 0xffff0000u);                        \
        float l0_ = x0_ - __uint_as_float(u0_ & 0xffff0000u);                 \
        float l1_ = x1_ - __uint_as_float(u1_ & 0xffff0000u);                 \
        al_.w[j_] = (__float_as_uint(l0_) >> 16) |                            \
                    (__float_as_uint(l1_) & 0xffff0000u);                     \
      }                                                                       \
      _Pragma("unroll") for (int ni_ = 0; ni_ < 4; ++ni_) {                   \
        acc[mi_][ni_] = __builtin_amdgcn_mfma_f32_16x16x32_bf16(              \
            ah_.v, bh_[ni_], acc[mi_][ni_], 0, 0, 0);                         \
        acc[mi_][ni_] = __builtin_amdgcn_mfma_f32_16x16x32_bf16(              \
            ah_.v, bl_[ni_], acc[mi_][ni_], 0, 0, 0);                         \
        acc[mi_][ni_] = __builtin_amdgcn_mfma_f32_16x16x32_bf16(              \
            al_.v, bh_[ni_], acc[mi_][ni_], 0, 0, 0);                         \
      }                                                                       \
    }                                                                         \
  } while (0)

  K1_GLOAD(X0, chunk0);
  K1_GLOAD(X1, chunk0 + 1);
  for (int cc = 0; cc < nchunk; cc += 4) {
    int ch = chunk0 + cc;
    K1_GLOAD(X2, ch + 2);
    K1_COMPUTE(X0, ch);
    K1_GLOAD(X3, ch + 3);
    K1_COMPUTE(X1, ch + 1);
    if (cc + 4 < nchunk) K1_GLOAD(X0, ch + 4);
    K1_COMPUTE(X2, ch + 2);
    if (cc + 5 < nchunk) K1_GLOAD(X1, ch + 5);
    K1_COMPUTE(X3, ch + 3);
  }
#undef K1_GLOAD
#undef K1_COMPUTE

  int base_c = ctile * 64 + wm * 32;
  float* dst = part + (size_t)p * 1048576;
#pragma unroll
  for (int mi = 0; mi < 2; ++mi)
#pragma unroll
    for (int ni = 0; ni < 4; ++ni) {
      int row0 = base_c + mi * 16 + kg * 4;
      int col = wn * 64 + ni * 16 + m16;
#pragma unroll
      for (int r = 0; r < 4; ++r)
        __builtin_nontemporal_store(acc[mi][ni][r],
                                    &dst[(size_t)(row0 + r) * 128 + col]);
    }
}

// k1b: reduce split-K partials -> g [8192][128] f32
__global__ __launch_bounds__(256) void k1b_reduce(const float* __restrict__ part,
                                                  float* __restrict__ g, int np) {
  int idx = blockIdx.x * 256 + threadIdx.x;
  float s = 0.f;
  for (int p = 0; p < np; ++p) s += part[(size_t)p * 1048576 + idx];
  g[idx] = s;
}

// ---------------------------------------------------------------------------
// k2: mode mix + irfft coefficient prep -> Afh/Afl bf16, k3-fragment-swizzled.
// (round-3 version: grid (16,8,16), g-slice in LDS, w streamed through L3)
// afidx(c,k) = (((c>>4)*4+(k>>5))*64 + ((k>>3)&3)*16 + (c&15))*8 + (k&7)
// ---------------------------------------------------------------------------
__global__ __launch_bounds__(256) void k2_mix(const float* __restrict__ g,
                                              const float* __restrict__ wre,
                                              const float* __restrict__ wim,
                                              unsigned short* __restrict__ Afh,
                                              unsigned short* __restrict__ Afl) {
  int oq = blockIdx.x;  // 16
  int h = blockIdx.y;   // 8
  int b = blockIdx.z;   // 16
  __shared__ float gre[64][64], gim[64][64];
  int t = threadIdx.x;
  int bh = b * 8 + h;
#pragma unroll
  for (int j = 0; j < 16; ++j) {
    int idx = j * 256 + t, ir = idx >> 6, mr = idx & 63;
    const float* row = &g[((size_t)bh * 64 + ir) * 128];
    gre[ir][mr] = row[mr];
    gim[ir][mr] = row[64 + mr];
  }
  __syncthreads();
  int o = oq * 4 + (t >> 6), m = t & 63;
  float are = 0.f, aim = 0.f;
  for (int i = 0; i < 64; ++i) {
    float gr = gre[i][m], gi = gim[i][m];
    int wofs = ((h * 64 + i) * 64 + o) * 64 + m;
    float wr = wre[wofs], wi = wim[wofs];
    are = fmaf(gr, wr, are);
    are = fmaf(-gi, wi, are);
    aim = fmaf(gr, wi, aim);
    aim = fmaf(gi, wr, aim);
  }
  const float invL = 1.0f / (float)L_FFT;
  float outre = are * ((m == 0) ? invL : 2.0f * invL);
  float outim = (m == 0) ? 0.0f : (-2.0f * invL) * aim;
  int c = bh * 64 + o;
  unsigned short h16, l16;
  {
    int k = m;
    int afidx = (((c >> 4) * 4 + (k >> 5)) * 64 + ((k >> 3) & 3) * 16 + (c & 15)) * 8 + (k & 7);
    split_bf16(outre, h16, l16);
    Afh[afidx] = h16;
    Afl[afidx] = l16;
  }
  {
    int k = 64 + m;
    int afidx = (((c >> 4) * 4 + (k >> 5)) * 64 + ((k >> 3) & 3) * 16 + (c & 15)) * 8 + (k & 7);
    split_bf16(outim, h16, l16);
    Afh[afidx] = h16;
    Afl[afidx] = l16;
  }
}

// ---------------------------------------------------------------------------
// k3: inverse GEMM, zero LDS, all operands fragment-swizzled & coalesced.
// y[c][l] = sum_k A[c][k] * T2[l][k]; block 128c x 128l, K=128 in 4 chunks.
// ---------------------------------------------------------------------------
__global__ __launch_bounds__(256) void k3_inverse(const unsigned short* __restrict__ Afh,
                                                  const unsigned short* __restrict__ Afl,
                                                  const unsigned short* __restrict__ T2fh,
                                                  const unsigned short* __restrict__ T2fl,
                                                  float* __restrict__ y) {
  int ltile = blockIdx.x;   // 0..31
  int c0 = blockIdx.y * 128;
  int t = threadIdx.x, wave = t >> 6, lane = t & 63;
  int wm = wave >> 1, wn = wave & 1, m16 = lane & 15, kg = lane >> 4;

  f32x4 acc[4][4] = {};

#pragma unroll
  for (int kc2 = 0; kc2 < 4; ++kc2) {
    bf16x8 bh[4], bl[4];
#pragma unroll
    for (int ni = 0; ni < 4; ++ni) {
      size_t off = ((size_t)((ltile * 8 + wn * 4 + ni) * 4 + kc2) << 9) + lane * 8;
      bh[ni] = *(const bf16x8*)(T2fh + off);
      bl[ni] = *(const bf16x8*)(T2fl + off);
    }
#pragma unroll
    for (int mi = 0; mi < 4; ++mi) {
      int c16 = (c0 >> 4) + wm * 4 + mi;
      size_t off = ((size_t)(c16 * 4 + kc2) << 9) + lane * 8;
      bf16x8 ah = *(const bf16x8*)(Afh + off);
      bf16x8 al = *(const bf16x8*)(Afl + off);
#pragma unroll
      for (int ni = 0; ni < 4; ++ni) {
        acc[mi][ni] = __builtin_amdgcn_mfma_f32_16x16x32_bf16(ah, bh[ni], acc[mi][ni], 0, 0, 0);
        acc[mi][ni] = __builtin_amdgcn_mfma_f32_16x16x32_bf16(ah, bl[ni], acc[mi][ni], 0, 0, 0);
        acc[mi][ni] = __builtin_amdgcn_mfma_f32_16x16x32_bf16(al, bh[ni], acc[mi][ni], 0, 0, 0);
      }
    }
  }

#pragma unroll
  for (int mi = 0; mi < 4; ++mi)
#pragma unroll
    for (int ni = 0; ni < 4; ++ni) {
      int row0 = c0 + wm * 64 + mi * 16 + kg * 4;
      int col = ltile * 128 + wn * 64 + ni * 16 + m16;
#pragma unroll
      for (int r = 0; r < 4; ++r)
        __builtin_nontemporal_store(acc[mi][ni][r],
                                    &y[(size_t)(row0 + r) * L_FFT + col]);
    }
}

// ---------------------------------------------------------------------------
extern "C" void kernel_launch(void* const* d_in, const int* in_sizes, int n_in,
                              void* d_out, int out_size, void* d_ws, size_t ws_size,
                              hipStream_t stream) {
  const float* q   = (const float*)d_in[0];
  const float* wre = (const float*)d_in[4];
  const float* wim = (const float*)d_in[5];
  const int* index = (const int*)d_in[6];
  float* y = (float*)d_out;
  char* ws = (char*)d_ws;

  // byte layout:
  // T1fh 1MB | T1fl 1MB | T2fh 1MB | T2fl 1MB | Afh 2MB | Afl 2MB | g 4MB |
  // ctab 16KB | stab 16KB | part np*4MB (at 13MB)
  unsigned short* T1fh = (unsigned short*)(ws);
  unsigned short* T1fl = (unsigned short*)(ws + (1u << 20));
  unsigned short* T2fh = (unsigned short*)(ws + (2u << 20));
  unsigned short* T2fl = (unsigned short*)(ws + (3u << 20));
  unsigned short* Afh  = (unsigned short*)(ws + (4u << 20));
  unsigned short* Afl  = (unsigned short*)(ws + (6u << 20));
  float* g             = (float*)(ws + (8u << 20));
  float* ctab          = (float*)(ws + (12u << 20));
  float* stab          = (float*)(ws + (12u << 20) + 16384);
  float* part          = (float*)(ws + (13u << 20));

  int np = 1;
  while (np < 8) {
    size_t need = (13u << 20) + (size_t)(np * 2) * (4u << 20);
    if (need <= ws_size) np *= 2; else break;
  }
  if ((13u << 20) + (size_t)np * (4u << 20) > ws_size) { np = 1; part = g; }
  int kspan = L_FFT / np;

  k0a_phase<<<dim3(16), dim3(256), 0, stream>>>(ctab, stab);
  k0b_expand<<<dim3(2048), dim3(256), 0, stream>>>(index, ctab, stab,
                                                   T1fh, T1fl, T2fh, T2fl);
  k1_forward<<<dim3(128, np), dim3(256), 0, stream>>>(q, T1fh, T1fl, part, kspan);
  if (np > 1)
    k1b_reduce<<<dim3(4096), dim3(256), 0, stream>>>(part, g, np);
  k2_mix<<<dim3(16, 8, 16), dim3(256), 0, stream>>>(g, wre, wim, Afh, Afl);
  k3_inverse<<<dim3(32, 64), dim3(256), 0, stream>>>(Afh, Afl, T2fh, T2fl, y);
}

// Round 8
// 117.732 us; speedup vs baseline: 1.1767x; 1.1767x over previous
//
#include <hip/hip_runtime.h>

#define L_FFT 4096
#define NCH 512

typedef __attribute__((ext_vector_type(8))) short bf16x8;
typedef __attribute__((ext_vector_type(4))) float f32x4;

__device__ __forceinline__ void split_bf16(float x, unsigned short& h, unsigned short& l) {
  unsigned u = __float_as_uint(x);
  h = (unsigned short)(u >> 16);                    // truncate -> hi
  float fh = __uint_as_float(u & 0xffff0000u);
  float lo = x - fh;                                // exact residual
  l = (unsigned short)(__float_as_uint(lo) >> 16);  // truncate -> lo
}

__device__ __forceinline__ void gload_lds16(const void* g, void* l) {
  __builtin_amdgcn_global_load_lds(
      (const __attribute__((address_space(1))) void*)g,
      (__attribute__((address_space(3))) void*)l, 16, 0, 0);
}

// ---------------------------------------------------------------------------
// k0a: phase tables ctab/stab[4096] = cos/sin(2*pi*ph/4096)
// ---------------------------------------------------------------------------
__global__ __launch_bounds__(256) void k0a_phase(float* __restrict__ ctab,
                                                 float* __restrict__ stab) {
  int i = blockIdx.x * 256 + threadIdx.x;  // 0..4095
  float s, c;
  sincosf(6.2831853071795864769f / 4096.f * (float)i, &s, &c);
  ctab[i] = c;
  stab[i] = s;
}

// ---------------------------------------------------------------------------
// k0b: expand phase tables into MFMA-fragment-swizzled bf16 hi/lo tables.
// T1f (forward B): idx = ((chunk*2+wn)*4+ni)*512 + lane*8 + i
//   kcol = wn*64+ni*16+(lane&15), l = chunk*32+(lane>>4)*8+i
// T2f (inverse B): idx = (lt16*4+kc2)*512 + lane*8 + i
//   l = lt16*16+(lane&15), k = kc2*32+(lane>>4)*8+i
// ---------------------------------------------------------------------------
__global__ __launch_bounds__(256) void k0b_expand(const int* __restrict__ index,
                                                  const float* __restrict__ ctab,
                                                  const float* __restrict__ stab,
                                                  unsigned short* __restrict__ T1fh,
                                                  unsigned short* __restrict__ T1fl,
                                                  unsigned short* __restrict__ T2fh,
                                                  unsigned short* __restrict__ T2fl) {
  int idx = blockIdx.x * 256 + threadIdx.x;  // 0..524287
  int i = idx & 7, lane = (idx >> 3) & 63;
  int m16 = lane & 15, kg = lane >> 4;
  {
    int ni = (idx >> 9) & 3, wn = (idx >> 11) & 1, chunk = idx >> 12;
    int kcol = wn * 64 + ni * 16 + m16;
    int l = chunk * 32 + kg * 8 + i;
    int f = index[kcol & 63];
    int ph = (l * f) & 4095;
    float v = (kcol < 64) ? ctab[ph] : -stab[ph];
    unsigned short h, lo;
    split_bf16(v, h, lo);
    T1fh[idx] = h;
    T1fl[idx] = lo;
  }
  {
    int kc2 = (idx >> 9) & 3, lt16 = idx >> 11;
    int l = lt16 * 16 + m16;
    int k = kc2 * 32 + kg * 8 + i;
    int ph = (l * (k & 63)) & 4095;
    float v = (k < 64) ? ctab[ph] : stab[ph];
    unsigned short h, lo;
    split_bf16(v, h, lo);
    T2fh[idx] = h;
    T2fl[idx] = lo;
  }
}

// ---------------------------------------------------------------------------
// k1: forward GEMM, 2-phase global_load_lds pipeline (m97 structure).
// part[p][c][k] = sum_l X[c,l]*T1[k,l]
// Block 128c x 128k, 4 waves (each 64x64 as 4x4 of 16x16x32), BK=32 l.
// A staged f32 in LDS [l=32][c=128], double-buffered, octet-XOR swizzled:
//   logical octet co (8 floats) of row l stored at physical octet co^(l>>3).
//   Staged via per-lane pre-swizzled GLOBAL addresses + linear LDS dest
//   (global_load_lds requirement); fragment reads apply the same XOR ->
//   2 lanes/bank (free). B operands direct from pre-swizzled global tables.
// ---------------------------------------------------------------------------
__global__ __launch_bounds__(256) void k1_forward(const float* __restrict__ q,
                                                  const unsigned short* __restrict__ T1fh,
                                                  const unsigned short* __restrict__ T1fl,
                                                  float* __restrict__ part,
                                                  int kspan) {
  int ctile = blockIdx.x;  // 0..63
  int p = blockIdx.y;
  int b = ctile >> 2, ch0 = (ctile & 3) * 128;
  int t = threadIdx.x, wave = t >> 6, lane = t & 63;
  int wm = wave >> 1, wn = wave & 1, m16 = lane & 15, kg = lane >> 4;
  int nt = kspan >> 5;
  int chunk0 = (p * kspan) >> 5;

  __shared__ float Xs[2 * 32 * 128];  // 32 KB, two 16 KB buffers

  f32x4 acc[4][4] = {};

// stage one 32x128 f32 tile: 4 rounds x 256 threads x 16B; row ll = j*8+(t>>5),
// 16B-slot p4 = t&31; global col cf = inverse-swizzled so LDS ends up at
// physical octet po = co ^ (ll>>3) with ll>>3 == j.
#define K1_STAGE(BUFBASE, CHUNK)                                              \
  do {                                                                        \
    _Pragma("unroll") for (int j_ = 0; j_ < 4; ++j_) {                        \
      int ll_ = j_ * 8 + (t >> 5);                                            \
      int p4_ = t & 31;                                                       \
      int cf_ = (((p4_ >> 1) ^ j_) << 3) + ((p4_ & 1) << 2);                  \
      const float* gs_ = q + ((size_t)b * L_FFT + (size_t)(CHUNK) * 32 + ll_) \
                                 * NCH + ch0 + cf_;                           \
      gload_lds16(gs_, &Xs[(BUFBASE) + ll_ * 128 + p4_ * 4]);                 \
    }                                                                         \
  } while (0)

#define K1_COMPUTE(BUFBASE, CHUNK)                                            \
  do {                                                                        \
    bf16x8 bh_[4], bl_[4];                                                    \
    _Pragma("unroll") for (int ni_ = 0; ni_ < 4; ++ni_) {                     \
      size_t off_ = ((size_t)(((CHUNK)*2 + wn) * 4 + ni_) << 9) + lane * 8;   \
      bh_[ni_] = *(const bf16x8*)(T1fh + off_);                               \
      bl_[ni_] = *(const bf16x8*)(T1fl + off_);                               \
    }                                                                         \
    _Pragma("unroll") for (int mi_ = 0; mi_ < 4; ++mi_) {                     \
      int c_ = wm * 64 + mi_ * 16 + m16;                                      \
      int p_ = (c_ & 7) + (((c_ >> 3) ^ kg) << 3);                            \
      float xf_[8];                                                           \
      _Pragma("unroll") for (int i_ = 0; i_ < 8; ++i_)                        \
        xf_[i_] = Xs[(BUFBASE) + (kg * 8 + i_) * 128 + p_];                   \
      union { bf16x8 v; unsigned w[4]; } ah_, al_;                            \
      _Pragma("unroll") for (int j_ = 0; j_ < 4; ++j_) {                      \
        float x0_ = xf_[2 * j_], x1_ = xf_[2 * j_ + 1];                       \
        unsigned u0_ = __float_as_uint(x0_), u1_ = __float_as_uint(x1_);      \
        ah_.w[j_] = (u0_ >> 16) | (u1_ & 0xffff0000u);                        \
        float l0_ = x0_ - __uint_as_float(u0_ & 0xffff0000u);                 \
        float l1_ = x1_ - __uint_as_float(u1_ & 0xffff0000u);                 \
        al_.w[j_] = (__float_as_uint(l0_) >> 16) |                            \
                    (__float_as_uint(l1_) & 0xffff0000u);                     \
      }                                                                       \
      _Pragma("unroll") for (int ni_ = 0; ni_ < 4; ++ni_) {                   \
        acc[mi_][ni_] = __builtin_amdgcn_mfma_f32_16x16x32_bf16(              \
            ah_.v, bh_[ni_], acc[mi_][ni_], 0, 0, 0);                         \
        acc[mi_][ni_] = __builtin_amdgcn_mfma_f32_16x16x32_bf16(              \
            ah_.v, bl_[ni_], acc[mi_][ni_], 0, 0, 0);                         \
        acc[mi_][ni_] = __builtin_amdgcn_mfma_f32_16x16x32_bf16(              \
            al_.v, bh_[ni_], acc[mi_][ni_], 0, 0, 0);                         \
      }                                                                       \
    }                                                                         \
  } while (0)

  K1_STAGE(0, chunk0);
  __syncthreads();
  for (int tt = 0; tt < nt; ++tt) {
    if (tt + 1 < nt) K1_STAGE(((tt + 1) & 1) * 4096, chunk0 + tt + 1);
    K1_COMPUTE((tt & 1) * 4096, chunk0 + tt);
    __syncthreads();
  }
#undef K1_STAGE
#undef K1_COMPUTE

  int base_c = ctile * 128 + wm * 64;
  float* dst = part + (size_t)p * 1048576;
#pragma unroll
  for (int mi = 0; mi < 4; ++mi)
#pragma unroll
    for (int ni = 0; ni < 4; ++ni) {
      int row0 = base_c + mi * 16 + kg * 4;
      int col = wn * 64 + ni * 16 + m16;
#pragma unroll
      for (int r = 0; r < 4; ++r)
        __builtin_nontemporal_store(acc[mi][ni][r],
                                    &dst[(size_t)(row0 + r) * 128 + col]);
    }
}

// k1b: reduce split-K partials -> g [8192][128] f32
__global__ __launch_bounds__(256) void k1b_reduce(const float* __restrict__ part,
                                                  float* __restrict__ g, int np) {
  int idx = blockIdx.x * 256 + threadIdx.x;
  float s = 0.f;
  for (int p = 0; p < np; ++p) s += part[(size_t)p * 1048576 + idx];
  g[idx] = s;
}

// ---------------------------------------------------------------------------
// k2: mode mix + irfft coefficient prep -> Afh/Afl bf16, k3-fragment-swizzled.
// (round-3 version: grid (16,8,16), g-slice in LDS, w streamed through L3)
// afidx(c,k) = (((c>>4)*4+(k>>5))*64 + ((k>>3)&3)*16 + (c&15))*8 + (k&7)
// ---------------------------------------------------------------------------
__global__ __launch_bounds__(256) void k2_mix(const float* __restrict__ g,
                                              const float* __restrict__ wre,
                                              const float* __restrict__ wim,
                                              unsigned short* __restrict__ Afh,
                                              unsigned short* __restrict__ Afl) {
  int oq = blockIdx.x;  // 16
  int h = blockIdx.y;   // 8
  int b = blockIdx.z;   // 16
  __shared__ float gre[64][64], gim[64][64];
  int t = threadIdx.x;
  int bh = b * 8 + h;
#pragma unroll
  for (int j = 0; j < 16; ++j) {
    int idx = j * 256 + t, ir = idx >> 6, mr = idx & 63;
    const float* row = &g[((size_t)bh * 64 + ir) * 128];
    gre[ir][mr] = row[mr];
    gim[ir][mr] = row[64 + mr];
  }
  __syncthreads();
  int o = oq * 4 + (t >> 6), m = t & 63;
  float are = 0.f, aim = 0.f;
  for (int i = 0; i < 64; ++i) {
    float gr = gre[i][m], gi = gim[i][m];
    int wofs = ((h * 64 + i) * 64 + o) * 64 + m;
    float wr = wre[wofs], wi = wim[wofs];
    are = fmaf(gr, wr, are);
    are = fmaf(-gi, wi, are);
    aim = fmaf(gr, wi, aim);
    aim = fmaf(gi, wr, aim);
  }
  const float invL = 1.0f / (float)L_FFT;
  float outre = are * ((m == 0) ? invL : 2.0f * invL);
  float outim = (m == 0) ? 0.0f : (-2.0f * invL) * aim;
  int c = bh * 64 + o;
  unsigned short h16, l16;
  {
    int k = m;
    int afidx = (((c >> 4) * 4 + (k >> 5)) * 64 + ((k >> 3) & 3) * 16 + (c & 15)) * 8 + (k & 7);
    split_bf16(outre, h16, l16);
    Afh[afidx] = h16;
    Afl[afidx] = l16;
  }
  {
    int k = 64 + m;
    int afidx = (((c >> 4) * 4 + (k >> 5)) * 64 + ((k >> 3) & 3) * 16 + (c & 15)) * 8 + (k & 7);
    split_bf16(outim, h16, l16);
    Afh[afidx] = h16;
    Afl[afidx] = l16;
  }
}

// ---------------------------------------------------------------------------
// k3: inverse GEMM, zero LDS, all operands fragment-swizzled & coalesced.
// y[c][l] = sum_k A[c][k] * T2[l][k]; block 128c x 128l, K=128 in 4 chunks.
// ---------------------------------------------------------------------------
__global__ __launch_bounds__(256) void k3_inverse(const unsigned short* __restrict__ Afh,
                                                  const unsigned short* __restrict__ Afl,
                                                  const unsigned short* __restrict__ T2fh,
                                                  const unsigned short* __restrict__ T2fl,
                                                  float* __restrict__ y) {
  int ltile = blockIdx.x;   // 0..31
  int c0 = blockIdx.y * 128;
  int t = threadIdx.x, wave = t >> 6, lane = t & 63;
  int wm = wave >> 1, wn = wave & 1, m16 = lane & 15, kg = lane >> 4;

  f32x4 acc[4][4] = {};

#pragma unroll
  for (int kc2 = 0; kc2 < 4; ++kc2) {
    bf16x8 bh[4], bl[4];
#pragma unroll
    for (int ni = 0; ni < 4; ++ni) {
      size_t off = ((size_t)((ltile * 8 + wn * 4 + ni) * 4 + kc2) << 9) + lane * 8;
      bh[ni] = *(const bf16x8*)(T2fh + off);
      bl[ni] = *(const bf16x8*)(T2fl + off);
    }
#pragma unroll
    for (int mi = 0; mi < 4; ++mi) {
      int c16 = (c0 >> 4) + wm * 4 + mi;
      size_t off = ((size_t)(c16 * 4 + kc2) << 9) + lane * 8;
      bf16x8 ah = *(const bf16x8*)(Afh + off);
      bf16x8 al = *(const bf16x8*)(Afl + off);
#pragma unroll
      for (int ni = 0; ni < 4; ++ni) {
        acc[mi][ni] = __builtin_amdgcn_mfma_f32_16x16x32_bf16(ah, bh[ni], acc[mi][ni], 0, 0, 0);
        acc[mi][ni] = __builtin_amdgcn_mfma_f32_16x16x32_bf16(ah, bl[ni], acc[mi][ni], 0, 0, 0);
        acc[mi][ni] = __builtin_amdgcn_mfma_f32_16x16x32_bf16(al, bh[ni], acc[mi][ni], 0, 0, 0);
      }
    }
  }

#pragma unroll
  for (int mi = 0; mi < 4; ++mi)
#pragma unroll
    for (int ni = 0; ni < 4; ++ni) {
      int row0 = c0 + wm * 64 + mi * 16 + kg * 4;
      int col = ltile * 128 + wn * 64 + ni * 16 + m16;
#pragma unroll
      for (int r = 0; r < 4; ++r)
        __builtin_nontemporal_store(acc[mi][ni][r],
                                    &y[(size_t)(row0 + r) * L_FFT + col]);
    }
}

// ---------------------------------------------------------------------------
extern "C" void kernel_launch(void* const* d_in, const int* in_sizes, int n_in,
                              void* d_out, int out_size, void* d_ws, size_t ws_size,
                              hipStream_t stream) {
  const float* q   = (const float*)d_in[0];
  const float* wre = (const float*)d_in[4];
  const float* wim = (const float*)d_in[5];
  const int* index = (const int*)d_in[6];
  float* y = (float*)d_out;
  char* ws = (char*)d_ws;

  // byte layout:
  // T1fh 1MB | T1fl 1MB | T2fh 1MB | T2fl 1MB | Afh 2MB | Afl 2MB | g 4MB |
  // ctab 16KB | stab 16KB | part np*4MB (at 13MB)
  unsigned short* T1fh = (unsigned short*)(ws);
  unsigned short* T1fl = (unsigned short*)(ws + (1u << 20));
  unsigned short* T2fh = (unsigned short*)(ws + (2u << 20));
  unsigned short* T2fl = (unsigned short*)(ws + (3u << 20));
  unsigned short* Afh  = (unsigned short*)(ws + (4u << 20));
  unsigned short* Afl  = (unsigned short*)(ws + (6u << 20));
  float* g             = (float*)(ws + (8u << 20));
  float* ctab          = (float*)(ws + (12u << 20));
  float* stab          = (float*)(ws + (12u << 20) + 16384);
  float* part          = (float*)(ws + (13u << 20));

  int np = 1;
  while (np < 8) {
    size_t need = (13u << 20) + (size_t)(np * 2) * (4u << 20);
    if (need <= ws_size) np *= 2; else break;
  }
  if ((13u << 20) + (size_t)np * (4u << 20) > ws_size) { np = 1; part = g; }
  int kspan = L_FFT / np;

  k0a_phase<<<dim3(16), dim3(256), 0, stream>>>(ctab, stab);
  k0b_expand<<<dim3(2048), dim3(256), 0, stream>>>(index, ctab, stab,
                                                   T1fh, T1fl, T2fh, T2fl);
  k1_forward<<<dim3(64, np), dim3(256), 0, stream>>>(q, T1fh, T1fl, part, kspan);
  if (np > 1)
    k1b_reduce<<<dim3(4096), dim3(256), 0, stream>>>(part, g, np);
  k2_mix<<<dim3(16, 8, 16), dim3(256), 0, stream>>>(g, wre, wim, Afh, Afl);
  k3_inverse<<<dim3(32, 64), dim3(256), 0, stream>>>(Afh, Afl, T2fh, T2fl, y);
}